// Round 6
// baseline (384.677 us; speedup 1.0000x reference)
//
#include <hip/hip_runtime.h>
#include <math.h>

typedef unsigned short u16;
typedef unsigned int   u32;

typedef __bf16 bf16x8 __attribute__((ext_vector_type(8)));
typedef float  f32x4  __attribute__((ext_vector_type(4)));

#define C_DIM 256
#define D_DIM 8192
#define HIDD  4096
#define Y0D   512
#define Y1D   2048

__device__ __forceinline__ u16 f2bf(float f) {
    union { float f; u32 u; } v; v.f = f;
    u32 r = v.u + 0x7fffu + ((v.u >> 16) & 1u);   // RNE
    return (u16)(r >> 16);
}
__device__ __forceinline__ float geluf(float x) {
    return 0.5f * x * (1.0f + erff(x * 0.70710678118654752f));
}
// LDS swizzle: 16B chunk kg within a 64B row, XOR'd by row bits -> <=2-way conflicts
__device__ __forceinline__ int swz(int row, int kg) {
    return row * 64 + (((kg) ^ ((row >> 1) & 3)) << 4);
}
// fp32 LDS swizzle for the filter row buffer
__device__ __forceinline__ int xsw(int t) {
    int ch = t >> 2;
    return (((ch ^ ((ch >> 3) & 7))) << 2) | (t & 3);
}

// ---- per-row: weight-net coefs (fused), Z=FIR(c,X-mu) bf16, Xo bf16, X bf16 ----
__global__ __launch_bounds__(256) void filterk(const float* __restrict__ X,
                                               const float* __restrict__ w1,
                                               const float* __restrict__ b1,
                                               const float* __restrict__ w2,
                                               const float* __restrict__ b2,
                                               u16* __restrict__ Zb,
                                               u16* __restrict__ Xob,
                                               u16* __restrict__ Xb) {
    __shared__ float Xl[8240];
    __shared__ float wl[65];
    __shared__ float cl[40];
    __shared__ float red[4];
    int i = blockIdx.x, tid = threadIdx.x;
    int lane = tid & 63, wv = tid >> 6;
    const float* row = X + (size_t)i * D_DIM;
    float s = 0.f;
    #pragma unroll
    for (int q = 0; q < 8; ++q) {
        int t = tid * 32 + q * 4;
        float4 v = *(const float4*)(row + t);
        s += v.x + v.y + v.z + v.w;
        *(float4*)(Xl + xsw(t)) = v;
    }
    // weight network, recomputed per block (cheap; saves a launch)
    float w1l = w1[lane], b1l = b1[lane], w2l = w2[lane], b2l = b2[0];
    for (int li = wv; li < 65; li += 4) {
        float lag = (float)(li - 32);
        float h = geluf(lag * w1l + b1l);
        float p = h * w2l;
        #pragma unroll
        for (int off = 32; off; off >>= 1) p += __shfl_xor(p, off);
        if (lane == 0) wl[li] = p + b2l;
    }
    #pragma unroll
    for (int off = 32; off; off >>= 1) s += __shfl_xor(s, off);
    if (lane == 0) red[wv] = s;
    __syncthreads();
    if (tid <= 32) {
        cl[tid] = (tid == 0) ? wl[32] / (float)D_DIM
                             : (wl[32 - tid] + wl[32 + tid]) / ((float)D_DIM - (float)tid);
    }
    if (tid == 33) {
        float ssum = wl[32] / (float)D_DIM;
        for (int k = 1; k <= 32; ++k) ssum += (wl[32 - k] + wl[32 + k]) / ((float)D_DIM - (float)k);
        cl[33] = ssum;
    }
    float mu = (red[0] + red[1] + red[2] + red[3]) * (1.f / (float)D_DIM);
    if (tid < 10) {  // pad window with mu => (pad - mu) contributes 0 == truncation
        float4 mv = make_float4(mu, mu, mu, mu);
        *(float4*)(Xl + xsw(D_DIM + tid * 4)) = mv;
    }
    __syncthreads();
    float csum = cl[33];
    #pragma unroll
    for (int ch = 0; ch < 8; ++ch) {
        int t4 = tid * 32 + ch * 4;
        float w[40] __attribute__((aligned(16)));
        #pragma unroll
        for (int g = 0; g < 10; ++g)
            *(float4*)(w + g * 4) = *(const float4*)(Xl + xsw(t4 + g * 4));
        u16 zb[4], xo[4], xb[4];
        #pragma unroll
        for (int j = 0; j < 4; ++j) {
            float a = 0.f;
            #pragma unroll
            for (int k = 0; k < 33; ++k) a = fmaf(cl[k], w[j + k], a);
            zb[j] = f2bf(a - mu * csum);   // Z = sum_k c_k*(x[t+k]-mu) over valid k
            xo[j] = f2bf(w[j] - mu);
            xb[j] = f2bf(w[j]);
        }
        uint2 zp, op, bp;
        zp.x = (u32)zb[0] | ((u32)zb[1] << 16); zp.y = (u32)zb[2] | ((u32)zb[3] << 16);
        op.x = (u32)xo[0] | ((u32)xo[1] << 16); op.y = (u32)xo[2] | ((u32)xo[3] << 16);
        bp.x = (u32)xb[0] | ((u32)xb[1] << 16); bp.y = (u32)xb[2] | ((u32)xb[3] << 16);
        *(uint2*)(Zb  + (size_t)i * D_DIM + t4) = zp;
        *(uint2*)(Xob + (size_t)i * D_DIM + t4) = op;
        *(uint2*)(Xb  + (size_t)i * D_DIM + t4) = bp;
    }
}

// ---------------- unified bf16 MFMA GEMM, 2-deep prefetch, 1 barrier/k-step ----
// BM=256, 512 thr (8 waves 4x2). MODE 0: bf16 split-K partials; MODE 2: fp32 out;
// MODE 3: bf16 out = gelu(acc + Vadd + bias). AF32: A fp32->bf16 staged.
// BT 0: B fp32 NN; BT 1: B bf16 NT (row-major n x K); BT 2: B bf16 NN.
template<int MODE, int AF32, int BT, int BN, int KS>
__global__ __launch_bounds__(512, 4) void gemm_u(
    const void* __restrict__ Av, int lda,
    const void* __restrict__ Bv, int ldb,
    int N, int sliceLen, int nHalf, long long bHalfOff,
    const float* __restrict__ Vadd, const float* __restrict__ bias,
    float* __restrict__ outF, u16* __restrict__ outB,
    int ldc, int partStride)
{
    constexpr int NI  = BN / 32;   // n-frags per wave
    constexpr int NPT = BN / 16;   // B elems staged per thread (NN paths)
    __shared__ u16 Alds[2][256 * 32];
    __shared__ u16 Blds[2][BN * 32];
    const int tid = threadIdx.x;
    const int bid = blockIdx.x;
    const int ks  = bid % KS;              // ks fastest -> same-ks blocks on one XCD
    const int nb0 = (bid / KS) * BN;
    const int mt  = blockIdx.y;
    const int k0base = ks * sliceLen;
    const int ksteps = sliceLen >> 5;      // must be even, >= 4
    const int lane = tid & 63, wv = tid >> 6;
    const int wm = wv >> 1, wn = wv & 1;

    const int inH2 = (nb0 >= nHalf) ? 1 : 0;
    const int nbB  = nb0 - (inH2 ? nHalf : 0);

    // A staging: thread covers 16 elements of one row
    const int sArow = tid >> 1, sAe = (tid & 1) * 16;
    const u16*   ApB = (const u16*)Av   + (size_t)(mt * 256 + sArow) * lda + sAe + k0base;
    const float* ApF = (const float*)Av + (size_t)(mt * 256 + sArow) * lda + sAe + k0base;
    const int aw0 = swz(sArow, sAe >> 3);
    const int aw1 = swz(sArow, (sAe >> 3) + 1);
    // B staging (NN): thread covers NPT elems of one k-row
    const int sBk = tid >> 4, sBn = (tid & 15) * NPT;
    const float* BpF = (const float*)Bv + (inH2 ? (size_t)bHalfOff : 0)
                       + (size_t)(k0base + sBk) * ldb + nbB + sBn;
    const u16*   BpH = (const u16*)Bv + (size_t)(k0base + sBk) * ldb + nbB + sBn;
    int bw[NPT];
    #pragma unroll
    for (int j = 0; j < NPT; ++j) bw[j] = swz(sBn + j, sBk >> 3) + (sBk & 7) * 2;
    // B staging (NT): thread covers 8 bf16 of one n-row
    const int sTrow = tid >> 2, sTkg = tid & 3;
    const u16* BpT = (const u16*)Bv + (size_t)(nb0 + sTrow) * ldb + k0base + sTkg * 8;
    const int bwT = swz(sTrow, sTkg);
    const bool doT = (tid < BN * 4);
    // fragment read offsets
    const int kg = lane >> 4, l15 = lane & 15;
    int aoff[4], boff[NI];
    #pragma unroll
    for (int mi = 0; mi < 4; ++mi) { int r = wm * 64 + mi * 16 + l15; aoff[mi] = swz(r, kg); }
    #pragma unroll
    for (int ni = 0; ni < NI; ++ni) { int r = wn * (BN / 2) + ni * 16 + l15; boff[ni] = swz(r, kg); }

    struct SR {
        int4 a0, a1;
        float4 fa0, fa1, fa2, fa3;
        float4 bf[(NPT + 3) / 4];
        int4 bt;
        u32 bh[(NPT + 1) / 2];
    };
    SR rE, rO;

    auto loadT = [&](int kt, SR& r) {
        if constexpr (AF32) {
            const float* ap = ApF + (kt << 5);
            r.fa0 = *(const float4*)(ap);     r.fa1 = *(const float4*)(ap + 4);
            r.fa2 = *(const float4*)(ap + 8); r.fa3 = *(const float4*)(ap + 12);
        } else {
            const u16* ap = ApB + (kt << 5);
            r.a0 = *(const int4*)(ap);
            r.a1 = *(const int4*)(ap + 8);
        }
        if constexpr (BT == 0) {
            const float* bp = BpF + (size_t)(kt << 5) * ldb;
            #pragma unroll
            for (int j = 0; j < NPT / 4; ++j) r.bf[j] = *(const float4*)(bp + j * 4);
        } else if constexpr (BT == 1) {
            if (doT) r.bt = *(const int4*)(BpT + (kt << 5));
        } else {
            const u16* bp = BpH + (size_t)(kt << 5) * ldb;
            #pragma unroll
            for (int j = 0; j < NPT / 2; ++j) r.bh[j] = *(const u32*)(bp + j * 2);
        }
    };
    auto writeT = [&](int pb, SR& r) {
        char* AB = (char*)Alds[pb];
        char* BB = (char*)Blds[pb];
        if constexpr (AF32) {
            int4 w0, w1;
            w0.x = (int)((u32)f2bf(r.fa0.x) | ((u32)f2bf(r.fa0.y) << 16));
            w0.y = (int)((u32)f2bf(r.fa0.z) | ((u32)f2bf(r.fa0.w) << 16));
            w0.z = (int)((u32)f2bf(r.fa1.x) | ((u32)f2bf(r.fa1.y) << 16));
            w0.w = (int)((u32)f2bf(r.fa1.z) | ((u32)f2bf(r.fa1.w) << 16));
            w1.x = (int)((u32)f2bf(r.fa2.x) | ((u32)f2bf(r.fa2.y) << 16));
            w1.y = (int)((u32)f2bf(r.fa2.z) | ((u32)f2bf(r.fa2.w) << 16));
            w1.z = (int)((u32)f2bf(r.fa3.x) | ((u32)f2bf(r.fa3.y) << 16));
            w1.w = (int)((u32)f2bf(r.fa3.z) | ((u32)f2bf(r.fa3.w) << 16));
            *(int4*)(AB + aw0) = w0;
            *(int4*)(AB + aw1) = w1;
        } else {
            *(int4*)(AB + aw0) = r.a0;
            *(int4*)(AB + aw1) = r.a1;
        }
        if constexpr (BT == 0) {
            #pragma unroll
            for (int j = 0; j < NPT; ++j) {
                float bj = ((const float*)r.bf)[j];
                *(u16*)(BB + bw[j]) = f2bf(bj);
            }
        } else if constexpr (BT == 1) {
            if (doT) *(int4*)(BB + bwT) = r.bt;
        } else {
            #pragma unroll
            for (int j = 0; j < NPT / 2; ++j) {
                *(u16*)(BB + bw[2 * j])     = (u16)(r.bh[j] & 0xffffu);
                *(u16*)(BB + bw[2 * j + 1]) = (u16)(r.bh[j] >> 16);
            }
        }
    };

    f32x4 acc[4][NI];
    #pragma unroll
    for (int mi = 0; mi < 4; ++mi)
        #pragma unroll
        for (int ni = 0; ni < NI; ++ni) { f32x4 zz = {0.f, 0.f, 0.f, 0.f}; acc[mi][ni] = zz; }

    // prologue: LDS[0] <- k0; rO holds k1; rE holds k2 (in flight)
    loadT(0, rE);
    loadT(1, rO);
    writeT(0, rE);
    loadT(2, rE);
    __syncthreads();

    #define MFMA_STEP(PB)                                                              \
        {                                                                              \
            const char* AB = (const char*)Alds[PB];                                    \
            const char* BB = (const char*)Blds[PB];                                    \
            bf16x8 af[4], bfr[NI];                                                     \
            _Pragma("unroll")                                                          \
            for (int mi = 0; mi < 4; ++mi) af[mi] = *(const bf16x8*)(AB + aoff[mi]);   \
            _Pragma("unroll")                                                          \
            for (int ni = 0; ni < NI; ++ni) bfr[ni] = *(const bf16x8*)(BB + boff[ni]); \
            _Pragma("unroll")                                                          \
            for (int mi = 0; mi < 4; ++mi)                                             \
                _Pragma("unroll")                                                      \
                for (int ni = 0; ni < NI; ++ni)                                        \
                    acc[mi][ni] = __builtin_amdgcn_mfma_f32_16x16x32_bf16(             \
                        af[mi], bfr[ni], acc[mi][ni], 0, 0, 0);                        \
        }

    for (int kt = 0; kt < ksteps; kt += 2) {
        // even phase: compute k(kt) from LDS0; stage k(kt+1) into LDS1
        writeT(1, rO);
        if (kt + 3 < ksteps) loadT(kt + 3, rO);
        MFMA_STEP(0);
        __syncthreads();
        // odd phase: compute k(kt+1) from LDS1; stage k(kt+2) into LDS0
        if (kt + 2 < ksteps) writeT(0, rE);
        if (kt + 4 < ksteps) loadT(kt + 4, rE);
        MFMA_STEP(1);
        __syncthreads();
    }
    #undef MFMA_STEP

    // epilogue: C/D layout col=lane&15, row=(lane>>4)*4+reg
    const int rq = lane >> 4;
    #pragma unroll
    for (int mi = 0; mi < 4; ++mi)
        #pragma unroll
        for (int ni = 0; ni < NI; ++ni)
            #pragma unroll
            for (int r = 0; r < 4; ++r) {
                int m = wm * 64 + mi * 16 + rq * 4 + r;
                int n = nb0 + wn * (BN / 2) + ni * 16 + l15;
                float v = acc[mi][ni][r];
                if (MODE == 0)
                    outB[(size_t)ks * partStride + (size_t)m * N + n] = f2bf(v);
                else if (MODE == 2)
                    outF[(size_t)(mt * 256 + m) * ldc + n] = v;
                else {  // MODE 3: gelu(acc + V + bias) -> bf16
                    float h = geluf(v + Vadd[(size_t)m * N + n] + bias[n]);
                    outB[(size_t)m * ldc + n] = f2bf(h);
                }
            }
}

// -------- sum 32 bf16 cov partials -> covbf ------------------------------------
__global__ __launch_bounds__(256) void reduce_cov(const u16* __restrict__ parts,
                                                  u16* __restrict__ out) {
    int i8 = (blockIdx.x * 256 + threadIdx.x) * 8;   // grid 32 -> 65536
    float s[8] = {};
    #pragma unroll
    for (int sl = 0; sl < 32; ++sl) {
        uint4 v = *(const uint4*)(parts + (size_t)sl * 65536 + i8);
        u32 w[4] = {v.x, v.y, v.z, v.w};
        #pragma unroll
        for (int j = 0; j < 4; ++j) {
            union { u32 u; float f; } lo, hi;
            lo.u = (w[j] & 0xffffu) << 16; hi.u = w[j] & 0xffff0000u;
            s[2 * j] += lo.f; s[2 * j + 1] += hi.f;
        }
    }
    uint4 pk;
    pk.x = (u32)f2bf(s[0]) | ((u32)f2bf(s[1]) << 16);
    pk.y = (u32)f2bf(s[2]) | ((u32)f2bf(s[3]) << 16);
    pk.z = (u32)f2bf(s[4]) | ((u32)f2bf(s[5]) << 16);
    pk.w = (u32)f2bf(s[6]) | ((u32)f2bf(s[7]) << 16);
    *(uint4*)(out + i8) = pk;
}

// -------- fc1 partials (8 slices of 256x8192) -> V fp32 (n<4096) / Ubf (n>=4096)
__global__ __launch_bounds__(256) void reduce_vu(const u16* __restrict__ parts,
                                                 float* __restrict__ V,
                                                 u16* __restrict__ U) {
    int i8 = (blockIdx.x * 256 + threadIdx.x) * 8;   // grid 1024 -> 2M
    int m = i8 >> 13, n = i8 & 8191;
    float s[8] = {};
    #pragma unroll
    for (int sl = 0; sl < 8; ++sl) {
        uint4 v = *(const uint4*)(parts + (size_t)sl * (256 * 8192) + i8);
        u32 w[4] = {v.x, v.y, v.z, v.w};
        #pragma unroll
        for (int j = 0; j < 4; ++j) {
            union { u32 u; float f; } lo, hi;
            lo.u = (w[j] & 0xffffu) << 16; hi.u = w[j] & 0xffff0000u;
            s[2 * j] += lo.f; s[2 * j + 1] += hi.f;
        }
    }
    if (n < 4096) {
        float* vp = V + (size_t)m * 4096 + n;
        *(float4*)(vp)     = make_float4(s[0], s[1], s[2], s[3]);
        *(float4*)(vp + 4) = make_float4(s[4], s[5], s[6], s[7]);
    } else {
        uint4 pk;
        pk.x = (u32)f2bf(s[0]) | ((u32)f2bf(s[1]) << 16);
        pk.y = (u32)f2bf(s[2]) | ((u32)f2bf(s[3]) << 16);
        pk.z = (u32)f2bf(s[4]) | ((u32)f2bf(s[5]) << 16);
        pk.w = (u32)f2bf(s[6]) | ((u32)f2bf(s[7]) << 16);
        *(uint4*)(U + (size_t)m * 4096 + (n - 4096)) = pk;
    }
}

// -------- fc2 partials (16 slices) + bias + gelu -> of32 fp32 ------------------
__global__ __launch_bounds__(256) void reduce_fc16(const u16* __restrict__ parts,
                                                   const float* __restrict__ bias,
                                                   float* __restrict__ outF) {
    int i8 = (blockIdx.x * 256 + threadIdx.x) * 8;   // grid 256 -> 512K
    int col = i8 & (Y1D - 1);
    float s[8] = {};
    #pragma unroll
    for (int sl = 0; sl < 16; ++sl) {
        uint4 v = *(const uint4*)(parts + (size_t)sl * (256 * Y1D) + i8);
        u32 w[4] = {v.x, v.y, v.z, v.w};
        #pragma unroll
        for (int j = 0; j < 4; ++j) {
            union { u32 u; float f; } lo, hi;
            lo.u = (w[j] & 0xffffu) << 16; hi.u = w[j] & 0xffff0000u;
            s[2 * j] += lo.f; s[2 * j + 1] += hi.f;
        }
    }
    float4 b0 = *(const float4*)(bias + col);
    float4 b1 = *(const float4*)(bias + col + 4);
    s[0] = geluf(s[0] + b0.x); s[1] = geluf(s[1] + b0.y);
    s[2] = geluf(s[2] + b0.z); s[3] = geluf(s[3] + b0.w);
    s[4] = geluf(s[4] + b1.x); s[5] = geluf(s[5] + b1.y);
    s[6] = geluf(s[6] + b1.z); s[7] = geluf(s[7] + b1.w);
    *(float4*)(outF + i8)     = make_float4(s[0], s[1], s[2], s[3]);
    *(float4*)(outF + i8 + 4) = make_float4(s[4], s[5], s[6], s[7]);
}

extern "C" void kernel_launch(void* const* d_in, const int* in_sizes, int n_in,
                              void* d_out, int out_size, void* d_ws, size_t ws_size,
                              hipStream_t stream) {
    const float* X     = (const float*)d_in[0];
    const float* wn_w1 = (const float*)d_in[1];
    const float* wn_b1 = (const float*)d_in[2];
    const float* wn_w2 = (const float*)d_in[3];
    const float* wn_b2 = (const float*)d_in[4];
    const float* fc1_w = (const float*)d_in[5];
    const float* fc1_b = (const float*)d_in[6];
    const float* fc2_w = (const float*)d_in[7];
    const float* fc2_b = (const float*)d_in[8];
    const float* proj  = (const float*)d_in[9];

    char* ws = (char*)d_ws;
    size_t off = 0;
    auto alloc = [&](size_t bytes) { size_t o = off; off += (bytes + 255) & ~(size_t)255; return o; };
    u16*   Zb    = (u16*)  (ws + alloc((size_t)C_DIM * D_DIM * 2));
    u16*   Xob   = (u16*)  (ws + alloc((size_t)C_DIM * D_DIM * 2));
    u16*   Xb    = (u16*)  (ws + alloc((size_t)C_DIM * D_DIM * 2));
    u16*   covp  = (u16*)  (ws + alloc((size_t)32 * 65536 * 2));
    u16*   covbf = (u16*)  (ws + alloc((size_t)65536 * 2));
    u16*   p1b   = (u16*)  (ws + alloc((size_t)8 * C_DIM * D_DIM * 2));
    float* Vf    = (float*)(ws + alloc((size_t)C_DIM * HIDD * 4));
    u16*   Ubf   = (u16*)  (ws + alloc((size_t)C_DIM * HIDD * 2));
    u16*   hbf   = (u16*)  (ws + alloc((size_t)C_DIM * HIDD * 2));
    u16*   p2b   = (u16*)  (ws + alloc((size_t)16 * C_DIM * Y1D * 2));
    float* of32  = (float*)(ws + alloc((size_t)C_DIM * Y1D * 4));

    filterk<<<C_DIM, 256, 0, stream>>>(X, wn_w1, wn_b1, wn_w2, wn_b2, Zb, Xob, Xb);
    // cov partials: Zb @ Xob^T (NT bf16 MFMA), KS=32 -> 128 blocks
    gemm_u<0, 0, 1, 64, 32><<<128, 512, 0, stream>>>(Zb, D_DIM, Xob, D_DIM,
        C_DIM, D_DIM / 32, C_DIM, 0, nullptr, nullptr, nullptr, covp, 0, 65536);
    reduce_cov<<<32, 256, 0, stream>>>(covp, covbf);
    // fc1 fused: Xb @ [W_top | W_bot] -> 8 bf16 K-slice partials of 256x8192
    gemm_u<0, 0, 0, 64, 8><<<(2 * HIDD / 64) * 8, 512, 0, stream>>>(Xb, D_DIM, fc1_w, HIDD,
        2 * HIDD, D_DIM / 8, HIDD, (long long)D_DIM * HIDD, nullptr, nullptr,
        nullptr, p1b, 0, C_DIM * 2 * HIDD);
    reduce_vu<<<1024, 256, 0, stream>>>(p1b, Vf, Ubf);
    // h = gelu(V + cov @ U + b1)  (K=256 small GEMM, BN=32 -> 128 blocks)
    gemm_u<3, 0, 2, 32, 1><<<HIDD / 32, 512, 0, stream>>>(covbf, C_DIM, Ubf, HIDD,
        HIDD, C_DIM, HIDD, 0, Vf, fc1_b, nullptr, hbf, HIDD, 0);
    // fc2: h @ fc2_w, KS=16 -> 512 blocks, bf16 partials
    gemm_u<0, 0, 0, 64, 16><<<(Y1D / 64) * 16, 512, 0, stream>>>(hbf, HIDD, fc2_w, Y1D,
        Y1D, HIDD / 16, Y1D, 0, nullptr, nullptr, nullptr, p2b, 0, C_DIM * Y1D);
    reduce_fc16<<<C_DIM * Y1D / 8 / 256, 256, 0, stream>>>(p2b, fc2_b, of32);
    // out = proj @ o   (A fp32 staged-converted; M=512 -> 2 m-tiles)
    gemm_u<2, 1, 0, 64, 1><<<dim3(Y1D / 64, 2), 512, 0, stream>>>(proj, C_DIM, of32, Y1D,
        Y1D, C_DIM, Y1D, 0, nullptr, nullptr, (float*)d_out, nullptr, Y1D, 0);
}

// Round 7
// 214.268 us; speedup vs baseline: 1.7953x; 1.7953x over previous
//
#include <hip/hip_runtime.h>
#include <math.h>

typedef unsigned short u16;
typedef unsigned int   u32;

typedef __bf16 bf16x8 __attribute__((ext_vector_type(8)));
typedef float  f32x4  __attribute__((ext_vector_type(4)));

#define C_DIM 256
#define D_DIM 8192
#define HIDD  4096
#define Y0D   512
#define Y1D   2048

__device__ __forceinline__ u16 f2bf(float f) {
    union { float f; u32 u; } v; v.f = f;
    u32 r = v.u + 0x7fffu + ((v.u >> 16) & 1u);   // RNE
    return (u16)(r >> 16);
}
__device__ __forceinline__ float geluf(float x) {
    return 0.5f * x * (1.0f + erff(x * 0.70710678118654752f));
}
// LDS swizzle: 16B chunk kg within a 64B row, XOR'd by row bits -> <=2-way conflicts
__device__ __forceinline__ int swz(int row, int kg) {
    return row * 64 + (((kg) ^ ((row >> 1) & 3)) << 4);
}
// fp32 LDS swizzle for the filter row buffer
__device__ __forceinline__ int xsw(int t) {
    int ch = t >> 2;
    return (((ch ^ ((ch >> 3) & 7))) << 2) | (t & 3);
}

// ---- per-row: weight-net coefs (fused), Z=FIR(c,X-mu) bf16, Xo bf16, X bf16 ----
__global__ __launch_bounds__(256) void filterk(const float* __restrict__ X,
                                               const float* __restrict__ w1,
                                               const float* __restrict__ b1,
                                               const float* __restrict__ w2,
                                               const float* __restrict__ b2,
                                               u16* __restrict__ Zb,
                                               u16* __restrict__ Xob,
                                               u16* __restrict__ Xb) {
    __shared__ float Xl[8240];
    __shared__ float wl[65];
    __shared__ float cl[40];
    __shared__ float red[4];
    int i = blockIdx.x, tid = threadIdx.x;
    int lane = tid & 63, wv = tid >> 6;
    const float* row = X + (size_t)i * D_DIM;
    float s = 0.f;
    #pragma unroll
    for (int q = 0; q < 8; ++q) {
        int t = tid * 32 + q * 4;
        float4 v = *(const float4*)(row + t);
        s += v.x + v.y + v.z + v.w;
        *(float4*)(Xl + xsw(t)) = v;
    }
    // weight network, recomputed per block (cheap; saves a launch)
    float w1l = w1[lane], b1l = b1[lane], w2l = w2[lane], b2l = b2[0];
    for (int li = wv; li < 65; li += 4) {
        float lag = (float)(li - 32);
        float h = geluf(lag * w1l + b1l);
        float p = h * w2l;
        #pragma unroll
        for (int off = 32; off; off >>= 1) p += __shfl_xor(p, off);
        if (lane == 0) wl[li] = p + b2l;
    }
    #pragma unroll
    for (int off = 32; off; off >>= 1) s += __shfl_xor(s, off);
    if (lane == 0) red[wv] = s;
    __syncthreads();
    if (tid <= 32) {
        cl[tid] = (tid == 0) ? wl[32] / (float)D_DIM
                             : (wl[32 - tid] + wl[32 + tid]) / ((float)D_DIM - (float)tid);
    }
    if (tid == 33) {
        float ssum = wl[32] / (float)D_DIM;
        for (int k = 1; k <= 32; ++k) ssum += (wl[32 - k] + wl[32 + k]) / ((float)D_DIM - (float)k);
        cl[33] = ssum;
    }
    float mu = (red[0] + red[1] + red[2] + red[3]) * (1.f / (float)D_DIM);
    if (tid < 10) {  // pad window with mu => (pad - mu) contributes 0 == truncation
        float4 mv = make_float4(mu, mu, mu, mu);
        *(float4*)(Xl + xsw(D_DIM + tid * 4)) = mv;
    }
    __syncthreads();
    float csum = cl[33];
    #pragma unroll
    for (int ch = 0; ch < 8; ++ch) {
        int t4 = tid * 32 + ch * 4;
        float w[40] __attribute__((aligned(16)));
        #pragma unroll
        for (int g = 0; g < 10; ++g)
            *(float4*)(w + g * 4) = *(const float4*)(Xl + xsw(t4 + g * 4));
        u16 zb[4], xo[4], xb[4];
        #pragma unroll
        for (int j = 0; j < 4; ++j) {
            float a = 0.f;
            #pragma unroll
            for (int k = 0; k < 33; ++k) a = fmaf(cl[k], w[j + k], a);
            zb[j] = f2bf(a - mu * csum);   // Z = sum_k c_k*(x[t+k]-mu) over valid k
            xo[j] = f2bf(w[j] - mu);
            xb[j] = f2bf(w[j]);
        }
        uint2 zp, op, bp;
        zp.x = (u32)zb[0] | ((u32)zb[1] << 16); zp.y = (u32)zb[2] | ((u32)zb[3] << 16);
        op.x = (u32)xo[0] | ((u32)xo[1] << 16); op.y = (u32)xo[2] | ((u32)xo[3] << 16);
        bp.x = (u32)xb[0] | ((u32)xb[1] << 16); bp.y = (u32)xb[2] | ((u32)xb[3] << 16);
        *(uint2*)(Zb  + (size_t)i * D_DIM + t4) = zp;
        *(uint2*)(Xob + (size_t)i * D_DIM + t4) = op;
        *(uint2*)(Xb  + (size_t)i * D_DIM + t4) = bp;
    }
}

// ------- unified bf16 MFMA GEMM, R5-proven 1-deep prefetch, 1 barrier/k-step ----
// BM=256, 512 thr (8 waves 4x2). MODE 0: bf16 split-K partials; MODE 2: fp32 out;
// MODE 3: bf16 out = gelu(acc + Vadd + bias). AF32: A fp32->bf16 staged.
// BT 0: B fp32 NN; BT 1: B bf16 NT (row-major n x K); BT 2: B bf16 NN.
template<int MODE, int AF32, int BT, int BN, int KS>
__global__ __launch_bounds__(512) void gemm_u(
    const void* __restrict__ Av, int lda,
    const void* __restrict__ Bv, int ldb,
    int N, int sliceLen, int nHalf, long long bHalfOff,
    const float* __restrict__ Vadd, const float* __restrict__ bias,
    float* __restrict__ outF, u16* __restrict__ outB,
    int ldc, int partStride)
{
    constexpr int NI  = BN / 32;   // n-frags per wave
    constexpr int NPT = BN / 16;   // B elems staged per thread (NN paths)
    __shared__ u16 Alds[2][256 * 32];
    __shared__ u16 Blds[2][BN * 32];
    const int tid = threadIdx.x;
    const int bid = blockIdx.x;
    const int ks  = bid % KS;              // ks fastest -> same-ks blocks on one XCD
    const int nb0 = (bid / KS) * BN;
    const int mt  = blockIdx.y;
    const int k0base = ks * sliceLen;
    const int ksteps = sliceLen >> 5;
    const int lane = tid & 63, wv = tid >> 6;
    const int wm = wv >> 1, wn = wv & 1;

    const int inH2 = (nb0 >= nHalf) ? 1 : 0;
    const int nbB  = nb0 - (inH2 ? nHalf : 0);

    // A staging: thread covers 16 elements of one row
    const int sArow = tid >> 1, sAe = (tid & 1) * 16;
    const u16*   ApB = (const u16*)Av   + (size_t)(mt * 256 + sArow) * lda + sAe + k0base;
    const float* ApF = (const float*)Av + (size_t)(mt * 256 + sArow) * lda + sAe + k0base;
    const int aw0 = swz(sArow, sAe >> 3);
    const int aw1 = swz(sArow, (sAe >> 3) + 1);
    // B staging (NN): thread covers NPT elems of one k-row
    const int sBk = tid >> 4, sBn = (tid & 15) * NPT;
    const float* BpF = (const float*)Bv + (inH2 ? (size_t)bHalfOff : 0)
                       + (size_t)(k0base + sBk) * ldb + nbB + sBn;
    const u16*   BpH = (const u16*)Bv + (size_t)(k0base + sBk) * ldb + nbB + sBn;
    int bw[NPT];
    #pragma unroll
    for (int j = 0; j < NPT; ++j) bw[j] = swz(sBn + j, sBk >> 3) + (sBk & 7) * 2;
    // B staging (NT): thread covers 8 bf16 of one n-row
    const int sTrow = tid >> 2, sTkg = tid & 3;
    const u16* BpT = (const u16*)Bv + (size_t)(nb0 + sTrow) * ldb + k0base + sTkg * 8;
    const int bwT = swz(sTrow, sTkg);
    const bool doT = (tid < BN * 4);
    // fragment read offsets
    const int kg = lane >> 4, l15 = lane & 15;
    int aoff[4], boff[NI];
    #pragma unroll
    for (int mi = 0; mi < 4; ++mi) { int r = wm * 64 + mi * 16 + l15; aoff[mi] = swz(r, kg); }
    #pragma unroll
    for (int ni = 0; ni < NI; ++ni) { int r = wn * (BN / 2) + ni * 16 + l15; boff[ni] = swz(r, kg); }

    // plain named locals (R5 style) — unused variants are DCE'd per template instance
    int4 av0, av1;
    float4 fa0, fa1, fa2, fa3;
    float4 bvv[(NPT + 3) / 4];
    int4 btv;
    u32 bhv[(NPT + 1) / 2];

    auto loadT = [&](int kt) {
        if constexpr (AF32) {
            const float* ap = ApF + (kt << 5);
            fa0 = *(const float4*)(ap);     fa1 = *(const float4*)(ap + 4);
            fa2 = *(const float4*)(ap + 8); fa3 = *(const float4*)(ap + 12);
        } else {
            const u16* ap = ApB + (kt << 5);
            av0 = *(const int4*)(ap);
            av1 = *(const int4*)(ap + 8);
        }
        if constexpr (BT == 0) {
            const float* bp = BpF + (size_t)(kt << 5) * ldb;
            #pragma unroll
            for (int j = 0; j < NPT / 4; ++j) bvv[j] = *(const float4*)(bp + j * 4);
        } else if constexpr (BT == 1) {
            if (doT) btv = *(const int4*)(BpT + (kt << 5));
        } else {
            const u16* bp = BpH + (size_t)(kt << 5) * ldb;
            #pragma unroll
            for (int j = 0; j < NPT / 2; ++j) bhv[j] = *(const u32*)(bp + j * 2);
        }
    };
    auto writeT = [&](int pb) {
        char* AB = (char*)Alds[pb];
        char* BB = (char*)Blds[pb];
        if constexpr (AF32) {
            int4 w0, w1;
            w0.x = (int)((u32)f2bf(fa0.x) | ((u32)f2bf(fa0.y) << 16));
            w0.y = (int)((u32)f2bf(fa0.z) | ((u32)f2bf(fa0.w) << 16));
            w0.z = (int)((u32)f2bf(fa1.x) | ((u32)f2bf(fa1.y) << 16));
            w0.w = (int)((u32)f2bf(fa1.z) | ((u32)f2bf(fa1.w) << 16));
            w1.x = (int)((u32)f2bf(fa2.x) | ((u32)f2bf(fa2.y) << 16));
            w1.y = (int)((u32)f2bf(fa2.z) | ((u32)f2bf(fa2.w) << 16));
            w1.z = (int)((u32)f2bf(fa3.x) | ((u32)f2bf(fa3.y) << 16));
            w1.w = (int)((u32)f2bf(fa3.z) | ((u32)f2bf(fa3.w) << 16));
            *(int4*)(AB + aw0) = w0;
            *(int4*)(AB + aw1) = w1;
        } else {
            *(int4*)(AB + aw0) = av0;
            *(int4*)(AB + aw1) = av1;
        }
        if constexpr (BT == 0) {
            #pragma unroll
            for (int j = 0; j < NPT; ++j) {
                float bj = ((const float*)bvv)[j];
                *(u16*)(BB + bw[j]) = f2bf(bj);
            }
        } else if constexpr (BT == 1) {
            if (doT) *(int4*)(BB + bwT) = btv;
        } else {
            #pragma unroll
            for (int j = 0; j < NPT / 2; ++j) {
                *(u16*)(BB + bw[2 * j])     = (u16)(bhv[j] & 0xffffu);
                *(u16*)(BB + bw[2 * j + 1]) = (u16)(bhv[j] >> 16);
            }
        }
    };

    f32x4 acc[4][NI];
    #pragma unroll
    for (int mi = 0; mi < 4; ++mi)
        #pragma unroll
        for (int ni = 0; ni < NI; ++ni) { f32x4 zz = {0.f, 0.f, 0.f, 0.f}; acc[mi][ni] = zz; }

    loadT(0); writeT(0); loadT(1);
    __syncthreads();
    for (int kt = 0; kt < ksteps; ++kt) {
        const int pb = kt & 1;
        if (kt + 1 < ksteps) writeT(pb ^ 1);
        if (kt + 2 < ksteps) loadT(kt + 2);
        const char* AB = (const char*)Alds[pb];
        const char* BB = (const char*)Blds[pb];
        bf16x8 af[4], bfr[NI];
        #pragma unroll
        for (int mi = 0; mi < 4; ++mi) af[mi] = *(const bf16x8*)(AB + aoff[mi]);
        #pragma unroll
        for (int ni = 0; ni < NI; ++ni) bfr[ni] = *(const bf16x8*)(BB + boff[ni]);
        #pragma unroll
        for (int mi = 0; mi < 4; ++mi)
            #pragma unroll
            for (int ni = 0; ni < NI; ++ni)
                acc[mi][ni] = __builtin_amdgcn_mfma_f32_16x16x32_bf16(af[mi], bfr[ni], acc[mi][ni], 0, 0, 0);
        __syncthreads();
    }

    // epilogue: C/D layout col=lane&15, row=(lane>>4)*4+reg
    const int rq = lane >> 4;
    #pragma unroll
    for (int mi = 0; mi < 4; ++mi)
        #pragma unroll
        for (int ni = 0; ni < NI; ++ni)
            #pragma unroll
            for (int r = 0; r < 4; ++r) {
                int m = wm * 64 + mi * 16 + rq * 4 + r;
                int n = nb0 + wn * (BN / 2) + ni * 16 + l15;
                float v = acc[mi][ni][r];
                if (MODE == 0)
                    outB[(size_t)ks * partStride + (size_t)m * N + n] = f2bf(v);
                else if (MODE == 2)
                    outF[(size_t)(mt * 256 + m) * ldc + n] = v;
                else {  // MODE 3: gelu(acc + V + bias) -> bf16
                    float h = geluf(v + Vadd[(size_t)m * N + n] + bias[n]);
                    outB[(size_t)m * ldc + n] = f2bf(h);
                }
            }
}

// -------- sum 32 bf16 cov partials -> covbf ------------------------------------
__global__ __launch_bounds__(256) void reduce_cov(const u16* __restrict__ parts,
                                                  u16* __restrict__ out) {
    int i8 = (blockIdx.x * 256 + threadIdx.x) * 8;   // grid 32 -> 65536
    float s[8] = {};
    #pragma unroll
    for (int sl = 0; sl < 32; ++sl) {
        uint4 v = *(const uint4*)(parts + (size_t)sl * 65536 + i8);
        u32 w[4] = {v.x, v.y, v.z, v.w};
        #pragma unroll
        for (int j = 0; j < 4; ++j) {
            union { u32 u; float f; } lo, hi;
            lo.u = (w[j] & 0xffffu) << 16; hi.u = w[j] & 0xffff0000u;
            s[2 * j] += lo.f; s[2 * j + 1] += hi.f;
        }
    }
    uint4 pk;
    pk.x = (u32)f2bf(s[0]) | ((u32)f2bf(s[1]) << 16);
    pk.y = (u32)f2bf(s[2]) | ((u32)f2bf(s[3]) << 16);
    pk.z = (u32)f2bf(s[4]) | ((u32)f2bf(s[5]) << 16);
    pk.w = (u32)f2bf(s[6]) | ((u32)f2bf(s[7]) << 16);
    *(uint4*)(out + i8) = pk;
}

// -------- fc1 partials (8 slices of 256x8192) -> V fp32 (n<4096) / Ubf (n>=4096)
__global__ __launch_bounds__(256) void reduce_vu(const u16* __restrict__ parts,
                                                 float* __restrict__ V,
                                                 u16* __restrict__ U) {
    int i8 = (blockIdx.x * 256 + threadIdx.x) * 8;   // grid 1024 -> 2M
    int m = i8 >> 13, n = i8 & 8191;
    float s[8] = {};
    #pragma unroll
    for (int sl = 0; sl < 8; ++sl) {
        uint4 v = *(const uint4*)(parts + (size_t)sl * (256 * 8192) + i8);
        u32 w[4] = {v.x, v.y, v.z, v.w};
        #pragma unroll
        for (int j = 0; j < 4; ++j) {
            union { u32 u; float f; } lo, hi;
            lo.u = (w[j] & 0xffffu) << 16; hi.u = w[j] & 0xffff0000u;
            s[2 * j] += lo.f; s[2 * j + 1] += hi.f;
        }
    }
    if (n < 4096) {
        float* vp = V + (size_t)m * 4096 + n;
        *(float4*)(vp)     = make_float4(s[0], s[1], s[2], s[3]);
        *(float4*)(vp + 4) = make_float4(s[4], s[5], s[6], s[7]);
    } else {
        uint4 pk;
        pk.x = (u32)f2bf(s[0]) | ((u32)f2bf(s[1]) << 16);
        pk.y = (u32)f2bf(s[2]) | ((u32)f2bf(s[3]) << 16);
        pk.z = (u32)f2bf(s[4]) | ((u32)f2bf(s[5]) << 16);
        pk.w = (u32)f2bf(s[6]) | ((u32)f2bf(s[7]) << 16);
        *(uint4*)(U + (size_t)m * 4096 + (n - 4096)) = pk;
    }
}

// -------- fc2 partials (16 slices) + bias + gelu -> of32 fp32 ------------------
__global__ __launch_bounds__(256) void reduce_fc16(const u16* __restrict__ parts,
                                                   const float* __restrict__ bias,
                                                   float* __restrict__ outF) {
    int i8 = (blockIdx.x * 256 + threadIdx.x) * 8;   // grid 256 -> 512K
    int col = i8 & (Y1D - 1);
    float s[8] = {};
    #pragma unroll
    for (int sl = 0; sl < 16; ++sl) {
        uint4 v = *(const uint4*)(parts + (size_t)sl * (256 * Y1D) + i8);
        u32 w[4] = {v.x, v.y, v.z, v.w};
        #pragma unroll
        for (int j = 0; j < 4; ++j) {
            union { u32 u; float f; } lo, hi;
            lo.u = (w[j] & 0xffffu) << 16; hi.u = w[j] & 0xffff0000u;
            s[2 * j] += lo.f; s[2 * j + 1] += hi.f;
        }
    }
    float4 b0 = *(const float4*)(bias + col);
    float4 b1 = *(const float4*)(bias + col + 4);
    s[0] = geluf(s[0] + b0.x); s[1] = geluf(s[1] + b0.y);
    s[2] = geluf(s[2] + b0.z); s[3] = geluf(s[3] + b0.w);
    s[4] = geluf(s[4] + b1.x); s[5] = geluf(s[5] + b1.y);
    s[6] = geluf(s[6] + b1.z); s[7] = geluf(s[7] + b1.w);
    *(float4*)(outF + i8)     = make_float4(s[0], s[1], s[2], s[3]);
    *(float4*)(outF + i8 + 4) = make_float4(s[4], s[5], s[6], s[7]);
}

extern "C" void kernel_launch(void* const* d_in, const int* in_sizes, int n_in,
                              void* d_out, int out_size, void* d_ws, size_t ws_size,
                              hipStream_t stream) {
    const float* X     = (const float*)d_in[0];
    const float* wn_w1 = (const float*)d_in[1];
    const float* wn_b1 = (const float*)d_in[2];
    const float* wn_w2 = (const float*)d_in[3];
    const float* wn_b2 = (const float*)d_in[4];
    const float* fc1_w = (const float*)d_in[5];
    const float* fc1_b = (const float*)d_in[6];
    const float* fc2_w = (const float*)d_in[7];
    const float* fc2_b = (const float*)d_in[8];
    const float* proj  = (const float*)d_in[9];

    char* ws = (char*)d_ws;
    size_t off = 0;
    auto alloc = [&](size_t bytes) { size_t o = off; off += (bytes + 255) & ~(size_t)255; return o; };
    u16*   Zb    = (u16*)  (ws + alloc((size_t)C_DIM * D_DIM * 2));
    u16*   Xob   = (u16*)  (ws + alloc((size_t)C_DIM * D_DIM * 2));
    u16*   Xb    = (u16*)  (ws + alloc((size_t)C_DIM * D_DIM * 2));
    u16*   covp  = (u16*)  (ws + alloc((size_t)32 * 65536 * 2));
    u16*   covbf = (u16*)  (ws + alloc((size_t)65536 * 2));
    u16*   p1b   = (u16*)  (ws + alloc((size_t)8 * C_DIM * D_DIM * 2));
    float* Vf    = (float*)(ws + alloc((size_t)C_DIM * HIDD * 4));
    u16*   Ubf   = (u16*)  (ws + alloc((size_t)C_DIM * HIDD * 2));
    u16*   hbf   = (u16*)  (ws + alloc((size_t)C_DIM * HIDD * 2));
    u16*   p2b   = (u16*)  (ws + alloc((size_t)16 * C_DIM * Y1D * 2));
    float* of32  = (float*)(ws + alloc((size_t)C_DIM * Y1D * 4));

    filterk<<<C_DIM, 256, 0, stream>>>(X, wn_w1, wn_b1, wn_w2, wn_b2, Zb, Xob, Xb);
    // cov partials: Zb @ Xob^T (NT bf16 MFMA), KS=32 -> 128 blocks
    gemm_u<0, 0, 1, 64, 32><<<128, 512, 0, stream>>>(Zb, D_DIM, Xob, D_DIM,
        C_DIM, D_DIM / 32, C_DIM, 0, nullptr, nullptr, nullptr, covp, 0, 65536);
    reduce_cov<<<32, 256, 0, stream>>>(covp, covbf);
    // fc1 fused: Xb @ [W_top | W_bot] -> 8 bf16 K-slice partials of 256x8192
    gemm_u<0, 0, 0, 64, 8><<<(2 * HIDD / 64) * 8, 512, 0, stream>>>(Xb, D_DIM, fc1_w, HIDD,
        2 * HIDD, D_DIM / 8, HIDD, (long long)D_DIM * HIDD, nullptr, nullptr,
        nullptr, p1b, 0, C_DIM * 2 * HIDD);
    reduce_vu<<<1024, 256, 0, stream>>>(p1b, Vf, Ubf);
    // h = gelu(V + cov @ U + b1)  (K=256 small GEMM, BN=32 -> 128 blocks)
    gemm_u<3, 0, 2, 32, 1><<<HIDD / 32, 512, 0, stream>>>(covbf, C_DIM, Ubf, HIDD,
        HIDD, C_DIM, HIDD, 0, Vf, fc1_b, nullptr, hbf, HIDD, 0);
    // fc2: h @ fc2_w, KS=16 -> 512 blocks, bf16 partials
    gemm_u<0, 0, 0, 64, 16><<<(Y1D / 64) * 16, 512, 0, stream>>>(hbf, HIDD, fc2_w, Y1D,
        Y1D, HIDD / 16, Y1D, 0, nullptr, nullptr, nullptr, p2b, 0, C_DIM * Y1D);
    reduce_fc16<<<C_DIM * Y1D / 8 / 256, 256, 0, stream>>>(p2b, fc2_b, of32);
    // out = proj @ o   (A fp32 staged-converted; M=512 -> 2 m-tiles)
    gemm_u<2, 1, 0, 64, 1><<<dim3(Y1D / 64, 2), 512, 0, stream>>>(proj, C_DIM, of32, Y1D,
        Y1D, C_DIM, Y1D, 0, nullptr, nullptr, (float*)d_out, nullptr, Y1D, 0);
}

// Round 8
// 192.854 us; speedup vs baseline: 1.9947x; 1.1110x over previous
//
#include <hip/hip_runtime.h>
#include <math.h>

typedef unsigned short u16;
typedef unsigned int   u32;

typedef __bf16 bf16x8 __attribute__((ext_vector_type(8)));
typedef float  f32x4  __attribute__((ext_vector_type(4)));

#define C_DIM 256
#define D_DIM 8192
#define HIDD  4096
#define Y0D   512
#define Y1D   2048

__device__ __forceinline__ u16 f2bf(float f) {
    union { float f; u32 u; } v; v.f = f;
    u32 r = v.u + 0x7fffu + ((v.u >> 16) & 1u);   // RNE
    return (u16)(r >> 16);
}
__device__ __forceinline__ float geluf(float x) {
    return 0.5f * x * (1.0f + erff(x * 0.70710678118654752f));
}
// LDS swizzle: 16B chunk kg within a 64B row, XOR'd by row bits -> <=2-way conflicts
__device__ __forceinline__ int swz(int row, int kg) {
    return row * 64 + (((kg) ^ ((row >> 1) & 3)) << 4);
}
// fp32 LDS swizzle for the filter row buffer
__device__ __forceinline__ int xsw(int t) {
    int ch = t >> 2;
    return (((ch ^ ((ch >> 3) & 7))) << 2) | (t & 3);
}

// ---- per-row: weight-net coefs (fused), Z=FIR(c,X-mu) bf16, Xo bf16, X bf16 ----
__global__ __launch_bounds__(256) void filterk(const float* __restrict__ X,
                                               const float* __restrict__ w1,
                                               const float* __restrict__ b1,
                                               const float* __restrict__ w2,
                                               const float* __restrict__ b2,
                                               u16* __restrict__ Zb,
                                               u16* __restrict__ Xob,
                                               u16* __restrict__ Xb) {
    __shared__ float Xl[8240];
    __shared__ float wl[65];
    __shared__ float cl[40];
    __shared__ float red[4];
    int i = blockIdx.x, tid = threadIdx.x;
    int lane = tid & 63, wv = tid >> 6;
    const float* row = X + (size_t)i * D_DIM;
    float s = 0.f;
    #pragma unroll
    for (int q = 0; q < 8; ++q) {
        int t = tid * 32 + q * 4;
        float4 v = *(const float4*)(row + t);
        s += v.x + v.y + v.z + v.w;
        *(float4*)(Xl + xsw(t)) = v;
    }
    // weight network, recomputed per block (cheap; saves a launch)
    float w1l = w1[lane], b1l = b1[lane], w2l = w2[lane], b2l = b2[0];
    for (int li = wv; li < 65; li += 4) {
        float lag = (float)(li - 32);
        float h = geluf(lag * w1l + b1l);
        float p = h * w2l;
        #pragma unroll
        for (int off = 32; off; off >>= 1) p += __shfl_xor(p, off);
        if (lane == 0) wl[li] = p + b2l;
    }
    #pragma unroll
    for (int off = 32; off; off >>= 1) s += __shfl_xor(s, off);
    if (lane == 0) red[wv] = s;
    __syncthreads();
    if (tid <= 32) {
        cl[tid] = (tid == 0) ? wl[32] / (float)D_DIM
                             : (wl[32 - tid] + wl[32 + tid]) / ((float)D_DIM - (float)tid);
    }
    if (tid == 33) {
        float ssum = wl[32] / (float)D_DIM;
        for (int k = 1; k <= 32; ++k) ssum += (wl[32 - k] + wl[32 + k]) / ((float)D_DIM - (float)k);
        cl[33] = ssum;
    }
    float mu = (red[0] + red[1] + red[2] + red[3]) * (1.f / (float)D_DIM);
    if (tid < 10) {  // pad window with mu => (pad - mu) contributes 0 == truncation
        float4 mv = make_float4(mu, mu, mu, mu);
        *(float4*)(Xl + xsw(D_DIM + tid * 4)) = mv;
    }
    __syncthreads();
    float csum = cl[33];
    #pragma unroll
    for (int ch = 0; ch < 8; ++ch) {
        int t4 = tid * 32 + ch * 4;
        float w[40] __attribute__((aligned(16)));
        #pragma unroll
        for (int g = 0; g < 10; ++g)
            *(float4*)(w + g * 4) = *(const float4*)(Xl + xsw(t4 + g * 4));
        u16 zb[4], xo[4], xb[4];
        #pragma unroll
        for (int j = 0; j < 4; ++j) {
            float a = 0.f;
            #pragma unroll
            for (int k = 0; k < 33; ++k) a = fmaf(cl[k], w[j + k], a);
            zb[j] = f2bf(a - mu * csum);   // Z = sum_k c_k*(x[t+k]-mu) over valid k
            xo[j] = f2bf(w[j] - mu);
            xb[j] = f2bf(w[j]);
        }
        uint2 zp, op, bp;
        zp.x = (u32)zb[0] | ((u32)zb[1] << 16); zp.y = (u32)zb[2] | ((u32)zb[3] << 16);
        op.x = (u32)xo[0] | ((u32)xo[1] << 16); op.y = (u32)xo[2] | ((u32)xo[3] << 16);
        bp.x = (u32)xb[0] | ((u32)xb[1] << 16); bp.y = (u32)xb[2] | ((u32)xb[3] << 16);
        *(uint2*)(Zb  + (size_t)i * D_DIM + t4) = zp;
        *(uint2*)(Xob + (size_t)i * D_DIM + t4) = op;
        *(uint2*)(Xb  + (size_t)i * D_DIM + t4) = bp;
    }
}

// ------- unified bf16 MFMA GEMM, 1 barrier/k-step; DEEP: B 2-tiles-ahead -------
// BM=256, 512 thr (8 waves 4x2). MODE 0: bf16 split-K partials; MODE 2: fp32 out;
// MODE 3: bf16 out = gelu(acc + Vadd + bias). AF32: A fp32->bf16 staged.
// BT 0: B fp32 NN; BT 1: B bf16 NT (row-major n x K); BT 2: B bf16 NN.
// DEEP=1 (BT==0 only): B registers prefetched 2 tiles ahead (named sets E/O)
// to cover ~900cy cold-HBM latency on streaming weights.
template<int MODE, int AF32, int BT, int BN, int KS, int DEEP>
__global__ __launch_bounds__(512) void gemm_u(
    const void* __restrict__ Av, int lda,
    const void* __restrict__ Bv, int ldb,
    int N, int sliceLen, int nHalf, long long bHalfOff,
    const float* __restrict__ Vadd, const float* __restrict__ bias,
    float* __restrict__ outF, u16* __restrict__ outB,
    int ldc, int partStride)
{
    static_assert(!DEEP || BT == 0, "DEEP only for fp32-B streaming path");
    constexpr int NI  = BN / 32;   // n-frags per wave
    constexpr int NPT = BN / 16;   // B elems staged per thread (NN paths)
    __shared__ u16 Alds[2][256 * 32];
    __shared__ u16 Blds[2][BN * 32];
    const int tid = threadIdx.x;
    const int bid = blockIdx.x;
    const int ks  = bid % KS;              // ks fastest -> same-ks blocks on one XCD
    const int nb0 = (bid / KS) * BN;
    const int mt  = blockIdx.y;
    const int k0base = ks * sliceLen;
    const int ksteps = sliceLen >> 5;      // DEEP requires even ksteps
    const int lane = tid & 63, wv = tid >> 6;
    const int wm = wv >> 1, wn = wv & 1;

    const int inH2 = (nb0 >= nHalf) ? 1 : 0;
    const int nbB  = nb0 - (inH2 ? nHalf : 0);

    // A staging: thread covers 16 elements of one row
    const int sArow = tid >> 1, sAe = (tid & 1) * 16;
    const u16*   ApB = (const u16*)Av   + (size_t)(mt * 256 + sArow) * lda + sAe + k0base;
    const float* ApF = (const float*)Av + (size_t)(mt * 256 + sArow) * lda + sAe + k0base;
    const int aw0 = swz(sArow, sAe >> 3);
    const int aw1 = swz(sArow, (sAe >> 3) + 1);
    // B staging (NN): thread covers NPT elems of one k-row
    const int sBk = tid >> 4, sBn = (tid & 15) * NPT;
    const float* BpF = (const float*)Bv + (inH2 ? (size_t)bHalfOff : 0)
                       + (size_t)(k0base + sBk) * ldb + nbB + sBn;
    const u16*   BpH = (const u16*)Bv + (size_t)(k0base + sBk) * ldb + nbB + sBn;
    int bw[NPT];
    #pragma unroll
    for (int j = 0; j < NPT; ++j) bw[j] = swz(sBn + j, sBk >> 3) + (sBk & 7) * 2;
    // B staging (NT): thread covers 8 bf16 of one n-row
    const int sTrow = tid >> 2, sTkg = tid & 3;
    const u16* BpT = (const u16*)Bv + (size_t)(nb0 + sTrow) * ldb + k0base + sTkg * 8;
    const int bwT = swz(sTrow, sTkg);
    const bool doT = (tid < BN * 4);
    // fragment read offsets
    const int kg = lane >> 4, l15 = lane & 15;
    int aoff[4], boff[NI];
    #pragma unroll
    for (int mi = 0; mi < 4; ++mi) { int r = wm * 64 + mi * 16 + l15; aoff[mi] = swz(r, kg); }
    #pragma unroll
    for (int ni = 0; ni < NI; ++ni) { int r = wn * (BN / 2) + ni * 16 + l15; boff[ni] = swz(r, kg); }

    // named register sets; unused variants DCE'd per template instance
    int4 av0, av1;
    float4 fa0, fa1, fa2, fa3;
    float4 bvvE[(NPT + 3) / 4];
    float4 bvvO[(NPT + 3) / 4];
    int4 btv;
    u32 bhv[(NPT + 1) / 2];

    auto loadA = [&](int kt) {
        if constexpr (AF32) {
            const float* ap = ApF + (kt << 5);
            fa0 = *(const float4*)(ap);     fa1 = *(const float4*)(ap + 4);
            fa2 = *(const float4*)(ap + 8); fa3 = *(const float4*)(ap + 12);
        } else {
            const u16* ap = ApB + (kt << 5);
            av0 = *(const int4*)(ap);
            av1 = *(const int4*)(ap + 8);
        }
    };
    auto loadB0 = [&](int kt, float4 (&d)[(NPT + 3) / 4]) {
        const float* bp = BpF + (size_t)(kt << 5) * ldb;
        #pragma unroll
        for (int j = 0; j < NPT / 4; ++j) d[j] = *(const float4*)(bp + j * 4);
    };
    auto loadBx = [&](int kt) {   // BT 1/2 paths
        if constexpr (BT == 1) {
            if (doT) btv = *(const int4*)(BpT + (kt << 5));
        } else if constexpr (BT == 2) {
            const u16* bp = BpH + (size_t)(kt << 5) * ldb;
            #pragma unroll
            for (int j = 0; j < NPT / 2; ++j) bhv[j] = *(const u32*)(bp + j * 2);
        }
    };
    auto writeA = [&](int pb) {
        char* AB = (char*)Alds[pb];
        if constexpr (AF32) {
            int4 w0, w1;
            w0.x = (int)((u32)f2bf(fa0.x) | ((u32)f2bf(fa0.y) << 16));
            w0.y = (int)((u32)f2bf(fa0.z) | ((u32)f2bf(fa0.w) << 16));
            w0.z = (int)((u32)f2bf(fa1.x) | ((u32)f2bf(fa1.y) << 16));
            w0.w = (int)((u32)f2bf(fa1.z) | ((u32)f2bf(fa1.w) << 16));
            w1.x = (int)((u32)f2bf(fa2.x) | ((u32)f2bf(fa2.y) << 16));
            w1.y = (int)((u32)f2bf(fa2.z) | ((u32)f2bf(fa2.w) << 16));
            w1.z = (int)((u32)f2bf(fa3.x) | ((u32)f2bf(fa3.y) << 16));
            w1.w = (int)((u32)f2bf(fa3.z) | ((u32)f2bf(fa3.w) << 16));
            *(int4*)(AB + aw0) = w0;
            *(int4*)(AB + aw1) = w1;
        } else {
            *(int4*)(AB + aw0) = av0;
            *(int4*)(AB + aw1) = av1;
        }
    };
    auto writeB0 = [&](int pb, const float4 (&d)[(NPT + 3) / 4]) {
        char* BB = (char*)Blds[pb];
        #pragma unroll
        for (int j = 0; j < NPT; ++j) {
            float bj = ((const float*)d)[j];
            *(u16*)(BB + bw[j]) = f2bf(bj);
        }
    };
    auto writeBx = [&](int pb) {
        char* BB = (char*)Blds[pb];
        if constexpr (BT == 1) {
            if (doT) *(int4*)(BB + bwT) = btv;
        } else if constexpr (BT == 2) {
            #pragma unroll
            for (int j = 0; j < NPT / 2; ++j) {
                *(u16*)(BB + bw[2 * j])     = (u16)(bhv[j] & 0xffffu);
                *(u16*)(BB + bw[2 * j + 1]) = (u16)(bhv[j] >> 16);
            }
        }
    };

    f32x4 acc[4][NI];
    #pragma unroll
    for (int mi = 0; mi < 4; ++mi)
        #pragma unroll
        for (int ni = 0; ni < NI; ++ni) { f32x4 zz = {0.f, 0.f, 0.f, 0.f}; acc[mi][ni] = zz; }

    auto mfmaStep = [&](int pb) {
        const char* AB = (const char*)Alds[pb];
        const char* BB = (const char*)Blds[pb];
        bf16x8 af[4], bfr[NI];
        #pragma unroll
        for (int mi = 0; mi < 4; ++mi) af[mi] = *(const bf16x8*)(AB + aoff[mi]);
        #pragma unroll
        for (int ni = 0; ni < NI; ++ni) bfr[ni] = *(const bf16x8*)(BB + boff[ni]);
        #pragma unroll
        for (int mi = 0; mi < 4; ++mi)
            #pragma unroll
            for (int ni = 0; ni < NI; ++ni)
                acc[mi][ni] = __builtin_amdgcn_mfma_f32_16x16x32_bf16(af[mi], bfr[ni], acc[mi][ni], 0, 0, 0);
    };

    if constexpr (DEEP) {
        // B prefetched 2 tiles ahead via named sets E/O; A 1 tile ahead (L2-warm).
        loadA(0); loadB0(0, bvvE);
        writeA(0); writeB0(0, bvvE);
        if (ksteps > 1) { loadA(1); loadB0(1, bvvO); }
        if (ksteps > 2) loadB0(2, bvvE);
        __syncthreads();
        for (int kt = 0; kt < ksteps; kt += 2) {
            // even: compute tile kt from LDS0; stage LDS1 <- tile kt+1
            writeA(1); writeB0(1, bvvO);
            if (kt + 2 < ksteps) loadA(kt + 2);
            if (kt + 3 < ksteps) loadB0(kt + 3, bvvO);
            mfmaStep(0);
            __syncthreads();
            // odd: compute tile kt+1 from LDS1; stage LDS0 <- tile kt+2
            if (kt + 2 < ksteps) { writeA(0); writeB0(0, bvvE); }
            if (kt + 3 < ksteps) loadA(kt + 3);
            if (kt + 4 < ksteps) loadB0(kt + 4, bvvE);
            mfmaStep(1);
            __syncthreads();
        }
    } else {
        loadA(0);
        if constexpr (BT == 0) loadB0(0, bvvE); else loadBx(0);
        writeA(0);
        if constexpr (BT == 0) writeB0(0, bvvE); else writeBx(0);
        loadA(1);
        if constexpr (BT == 0) loadB0(1, bvvE); else loadBx(1);
        __syncthreads();
        for (int kt = 0; kt < ksteps; ++kt) {
            const int pb = kt & 1;
            if (kt + 1 < ksteps) {
                writeA(pb ^ 1);
                if constexpr (BT == 0) writeB0(pb ^ 1, bvvE); else writeBx(pb ^ 1);
            }
            if (kt + 2 < ksteps) {
                loadA(kt + 2);
                if constexpr (BT == 0) loadB0(kt + 2, bvvE); else loadBx(kt + 2);
            }
            mfmaStep(pb);
            __syncthreads();
        }
    }

    // epilogue: C/D layout col=lane&15, row=(lane>>4)*4+reg
    const int rq = lane >> 4;
    #pragma unroll
    for (int mi = 0; mi < 4; ++mi)
        #pragma unroll
        for (int ni = 0; ni < NI; ++ni)
            #pragma unroll
            for (int r = 0; r < 4; ++r) {
                int m = wm * 64 + mi * 16 + rq * 4 + r;
                int n = nb0 + wn * (BN / 2) + ni * 16 + l15;
                float v = acc[mi][ni][r];
                if (MODE == 0)
                    outB[(size_t)ks * partStride + (size_t)m * N + n] = f2bf(v);
                else if (MODE == 2)
                    outF[(size_t)(mt * 256 + m) * ldc + n] = v;
                else {  // MODE 3: gelu(acc + V + bias) -> bf16
                    float h = geluf(v + Vadd[(size_t)m * N + n] + bias[n]);
                    outB[(size_t)m * ldc + n] = f2bf(h);
                }
            }
}

// -------- sum 32 bf16 cov partials -> covbf ------------------------------------
__global__ __launch_bounds__(256) void reduce_cov(const u16* __restrict__ parts,
                                                  u16* __restrict__ out) {
    int i8 = (blockIdx.x * 256 + threadIdx.x) * 8;   // grid 32 -> 65536
    float s[8] = {};
    #pragma unroll
    for (int sl = 0; sl < 32; ++sl) {
        uint4 v = *(const uint4*)(parts + (size_t)sl * 65536 + i8);
        u32 w[4] = {v.x, v.y, v.z, v.w};
        #pragma unroll
        for (int j = 0; j < 4; ++j) {
            union { u32 u; float f; } lo, hi;
            lo.u = (w[j] & 0xffffu) << 16; hi.u = w[j] & 0xffff0000u;
            s[2 * j] += lo.f; s[2 * j + 1] += hi.f;
        }
    }
    uint4 pk;
    pk.x = (u32)f2bf(s[0]) | ((u32)f2bf(s[1]) << 16);
    pk.y = (u32)f2bf(s[2]) | ((u32)f2bf(s[3]) << 16);
    pk.z = (u32)f2bf(s[4]) | ((u32)f2bf(s[5]) << 16);
    pk.w = (u32)f2bf(s[6]) | ((u32)f2bf(s[7]) << 16);
    *(uint4*)(out + i8) = pk;
}

// -------- fc1 partials (8 slices of 256x8192) -> V fp32 (n<4096) / Ubf (n>=4096)
__global__ __launch_bounds__(256) void reduce_vu(const u16* __restrict__ parts,
                                                 float* __restrict__ V,
                                                 u16* __restrict__ U) {
    int i8 = (blockIdx.x * 256 + threadIdx.x) * 8;   // grid 1024 -> 2M
    int m = i8 >> 13, n = i8 & 8191;
    float s[8] = {};
    #pragma unroll
    for (int sl = 0; sl < 8; ++sl) {
        uint4 v = *(const uint4*)(parts + (size_t)sl * (256 * 8192) + i8);
        u32 w[4] = {v.x, v.y, v.z, v.w};
        #pragma unroll
        for (int j = 0; j < 4; ++j) {
            union { u32 u; float f; } lo, hi;
            lo.u = (w[j] & 0xffffu) << 16; hi.u = w[j] & 0xffff0000u;
            s[2 * j] += lo.f; s[2 * j + 1] += hi.f;
        }
    }
    if (n < 4096) {
        float* vp = V + (size_t)m * 4096 + n;
        *(float4*)(vp)     = make_float4(s[0], s[1], s[2], s[3]);
        *(float4*)(vp + 4) = make_float4(s[4], s[5], s[6], s[7]);
    } else {
        uint4 pk;
        pk.x = (u32)f2bf(s[0]) | ((u32)f2bf(s[1]) << 16);
        pk.y = (u32)f2bf(s[2]) | ((u32)f2bf(s[3]) << 16);
        pk.z = (u32)f2bf(s[4]) | ((u32)f2bf(s[5]) << 16);
        pk.w = (u32)f2bf(s[6]) | ((u32)f2bf(s[7]) << 16);
        *(uint4*)(U + (size_t)m * 4096 + (n - 4096)) = pk;
    }
}

// -------- fc2 partials (16 slices) + bias + gelu -> of32 fp32 ------------------
__global__ __launch_bounds__(256) void reduce_fc16(const u16* __restrict__ parts,
                                                   const float* __restrict__ bias,
                                                   float* __restrict__ outF) {
    int i8 = (blockIdx.x * 256 + threadIdx.x) * 8;   // grid 256 -> 512K
    int col = i8 & (Y1D - 1);
    float s[8] = {};
    #pragma unroll
    for (int sl = 0; sl < 16; ++sl) {
        uint4 v = *(const uint4*)(parts + (size_t)sl * (256 * Y1D) + i8);
        u32 w[4] = {v.x, v.y, v.z, v.w};
        #pragma unroll
        for (int j = 0; j < 4; ++j) {
            union { u32 u; float f; } lo, hi;
            lo.u = (w[j] & 0xffffu) << 16; hi.u = w[j] & 0xffff0000u;
            s[2 * j] += lo.f; s[2 * j + 1] += hi.f;
        }
    }
    float4 b0 = *(const float4*)(bias + col);
    float4 b1 = *(const float4*)(bias + col + 4);
    s[0] = geluf(s[0] + b0.x); s[1] = geluf(s[1] + b0.y);
    s[2] = geluf(s[2] + b0.z); s[3] = geluf(s[3] + b0.w);
    s[4] = geluf(s[4] + b1.x); s[5] = geluf(s[5] + b1.y);
    s[6] = geluf(s[6] + b1.z); s[7] = geluf(s[7] + b1.w);
    *(float4*)(outF + i8)     = make_float4(s[0], s[1], s[2], s[3]);
    *(float4*)(outF + i8 + 4) = make_float4(s[4], s[5], s[6], s[7]);
}

extern "C" void kernel_launch(void* const* d_in, const int* in_sizes, int n_in,
                              void* d_out, int out_size, void* d_ws, size_t ws_size,
                              hipStream_t stream) {
    const float* X     = (const float*)d_in[0];
    const float* wn_w1 = (const float*)d_in[1];
    const float* wn_b1 = (const float*)d_in[2];
    const float* wn_w2 = (const float*)d_in[3];
    const float* wn_b2 = (const float*)d_in[4];
    const float* fc1_w = (const float*)d_in[5];
    const float* fc1_b = (const float*)d_in[6];
    const float* fc2_w = (const float*)d_in[7];
    const float* fc2_b = (const float*)d_in[8];
    const float* proj  = (const float*)d_in[9];

    char* ws = (char*)d_ws;
    size_t off = 0;
    auto alloc = [&](size_t bytes) { size_t o = off; off += (bytes + 255) & ~(size_t)255; return o; };
    u16*   Zb    = (u16*)  (ws + alloc((size_t)C_DIM * D_DIM * 2));
    u16*   Xob   = (u16*)  (ws + alloc((size_t)C_DIM * D_DIM * 2));
    u16*   Xb    = (u16*)  (ws + alloc((size_t)C_DIM * D_DIM * 2));
    u16*   covp  = (u16*)  (ws + alloc((size_t)32 * 65536 * 2));
    u16*   covbf = (u16*)  (ws + alloc((size_t)65536 * 2));
    u16*   p1b   = (u16*)  (ws + alloc((size_t)8 * C_DIM * D_DIM * 2));
    float* Vf    = (float*)(ws + alloc((size_t)C_DIM * HIDD * 4));
    u16*   Ubf   = (u16*)  (ws + alloc((size_t)C_DIM * HIDD * 2));
    u16*   hbf   = (u16*)  (ws + alloc((size_t)C_DIM * HIDD * 2));
    u16*   p2b   = (u16*)  (ws + alloc((size_t)16 * C_DIM * Y1D * 2));
    float* of32  = (float*)(ws + alloc((size_t)C_DIM * Y1D * 4));

    filterk<<<C_DIM, 256, 0, stream>>>(X, wn_w1, wn_b1, wn_w2, wn_b2, Zb, Xob, Xb);
    // cov partials: Zb @ Xob^T (NT bf16 MFMA), KS=32 -> 128 blocks
    gemm_u<0, 0, 1, 64, 32, 0><<<128, 512, 0, stream>>>(Zb, D_DIM, Xob, D_DIM,
        C_DIM, D_DIM / 32, C_DIM, 0, nullptr, nullptr, nullptr, covp, 0, 65536);
    reduce_cov<<<32, 256, 0, stream>>>(covp, covbf);
    // fc1 fused: Xb @ [W_top | W_bot] -> 8 bf16 K-slice partials, DEEP B prefetch
    gemm_u<0, 0, 0, 64, 8, 1><<<(2 * HIDD / 64) * 8, 512, 0, stream>>>(Xb, D_DIM, fc1_w, HIDD,
        2 * HIDD, D_DIM / 8, HIDD, (long long)D_DIM * HIDD, nullptr, nullptr,
        nullptr, p1b, 0, C_DIM * 2 * HIDD);
    reduce_vu<<<1024, 256, 0, stream>>>(p1b, Vf, Ubf);
    // h = gelu(V + cov @ U + b1)  (K=256 small GEMM, BN=32 -> 128 blocks)
    gemm_u<3, 0, 2, 32, 1, 0><<<HIDD / 32, 512, 0, stream>>>(covbf, C_DIM, Ubf, HIDD,
        HIDD, C_DIM, HIDD, 0, Vf, fc1_b, nullptr, hbf, HIDD, 0);
    // fc2: h @ fc2_w, KS=16 -> 512 blocks, bf16 partials, DEEP B prefetch
    gemm_u<0, 0, 0, 64, 16, 1><<<(Y1D / 64) * 16, 512, 0, stream>>>(hbf, HIDD, fc2_w, Y1D,
        Y1D, HIDD / 16, Y1D, 0, nullptr, nullptr, nullptr, p2b, 0, C_DIM * Y1D);
    reduce_fc16<<<C_DIM * Y1D / 8 / 256, 256, 0, stream>>>(p2b, fc2_b, of32);
    // out = proj @ o   (A fp32 staged-converted; M=512 -> 2 m-tiles)
    gemm_u<2, 1, 0, 64, 1, 0><<<dim3(Y1D / 64, 2), 512, 0, stream>>>(proj, C_DIM, of32, Y1D,
        Y1D, C_DIM, Y1D, 0, nullptr, nullptr, (float*)d_out, nullptr, Y1D, 0);
}